// Round 7
// baseline (389.155 us; speedup 1.0000x reference)
//
#include <hip/hip_runtime.h>
#include <math.h>

#define B_SZ    2
#define L_SEQ   2048
#define D_MODEL 1024
#define D_INNER 2048
#define D_STATE 16
#define DT_RANK 64
#define MM      (B_SZ * L_SEQ)   // 4096 rows
#define NCH     64               // scan chunks
#define CLEN    (L_SEQ / NCH)    // 32 steps per chunk
#define PFD     8                // scan prefetch depth

typedef _Float16 h8v __attribute__((ext_vector_type(8)));
typedef _Float16 h4v __attribute__((ext_vector_type(4)));
typedef float f32x4 __attribute__((ext_vector_type(4)));

// Async global->LDS DMA, 16B per lane. LDS dest = uniform base + lane*16.
__device__ __forceinline__ void gload16(const void* g, void* l) {
    __builtin_amdgcn_global_load_lds((const __attribute__((address_space(1))) void*)g,
                                     (__attribute__((address_space(3))) void*)l, 16, 0, 0);
}

// ---------------------------------------------------------------------------
// prep: all weight transposes (fp32 -> fp16 T[N][K]) + x -> fp16 cast.
// ---------------------------------------------------------------------------
__global__ __launch_bounds__(256) void prep(const float* __restrict__ x,
                                            _Float16* __restrict__ xf16,
                                            const float* __restrict__ W_in,
                                            _Float16* __restrict__ WinT,
                                            const float* __restrict__ W_x,
                                            _Float16* __restrict__ WxT,
                                            const float* __restrict__ W_dt,
                                            _Float16* __restrict__ WdtT,
                                            const float* __restrict__ W_out,
                                            _Float16* __restrict__ WoutT) {
    __shared__ float t[32][33];
    const int b = blockIdx.x;
    const float* W; _Float16* T; int K, N, tile;
    if (b < 4096)      { W = W_in;  T = WinT;  K = 1024; N = 4096; tile = b; }
    else if (b < 4288) { W = W_x;   T = WxT;   K = 2048; N = 96;   tile = b - 4096; }
    else if (b < 4416) { W = W_dt;  T = WdtT;  K = 64;   N = 2048; tile = b - 4288; }
    else if (b < 6464) { W = W_out; T = WoutT; K = 2048; N = 1024; tile = b - 4416; }
    else {
        int idx = (b - 6464) * 256 + threadIdx.x;
        float4 v = ((const float4*)x)[idx];
        h4v h = {(_Float16)v.x, (_Float16)v.y, (_Float16)v.z, (_Float16)v.w};
        *(h4v*)(xf16 + (size_t)idx * 4) = h;
        return;
    }
    const int ntx = N / 32;
    const int k0 = (tile / ntx) * 32, n0 = (tile % ntx) * 32;
    #pragma unroll
    for (int i = 0; i < 4; ++i) {
        int idx = threadIdx.x + i * 256;
        int r = idx >> 5, c = idx & 31;
        t[r][c] = W[(size_t)(k0 + r) * N + n0 + c];
    }
    __syncthreads();
    #pragma unroll
    for (int i = 0; i < 4; ++i) {
        int idx = threadIdx.x + i * 256;
        int n = idx >> 5, k = idx & 31;
        T[(size_t)(n0 + n) * K + k0 + k] = (_Float16)t[k][n];
    }
}

// ---------------------------------------------------------------------------
// fp16 MFMA GEMM, double-buffered async DMA: C = A[M][K] @ Bt[N][K]^T.
// 128x128 tile, 256 thr, 4 waves 2x2, wave 64x64 (4x4 16x16x32 frags), BK=32.
// K-loop: issue DMA(k+1) -> MFMA(k) -> barrier(drains DMA) -- the vmcnt drain
// overlaps this block's own MFMA burst (breaks the R6 issue->drain->MFMA
// convoy that held MfmaUtil at 20%).
// LDS XOR-swizzled at 16B granularity via the global source address per lane.
// EPI 0: fp32 C. EPI 2: cols<2048 -> fp16 H (xs); cols>=2048 -> silu -> Hg.
// ---------------------------------------------------------------------------
template<int EPI>
__global__ __launch_bounds__(256) void gemm_f16(const _Float16* __restrict__ A,
                                                const _Float16* __restrict__ Bt,
                                                float* __restrict__ C,
                                                _Float16* __restrict__ H,
                                                _Float16* __restrict__ Hg,
                                                int M, int N, int K, int ldc) {
    __shared__ _Float16 sA[2][128 * 32];
    __shared__ _Float16 sB[2][128 * 32];

    const int tid = threadIdx.x;
    const int wave = tid >> 6, lane = tid & 63;
    const int bm = blockIdx.y * 128, bn = blockIdx.x * 128;

    const int lrow = lane >> 2, pc = lane & 3;
    const int ar = wave * 32 + lrow;
    const size_t gA = (size_t)(bm + ar) * K + ((pc ^ ((ar >> 1) & 3)) * 8);
    const size_t gB = (size_t)(bn + ar) * K + ((pc ^ ((ar >> 1) & 3)) * 8);
    const int lofs = (wave * 32) * 32;

    const int lm = lane & 15, lq = lane >> 4;
    const int rofs = (lq ^ ((lm >> 1) & 3)) * 8;
    const int wm = (wave >> 1) * 64, wn = (wave & 1) * 64;

    f32x4 acc[4][4];
    #pragma unroll
    for (int i = 0; i < 4; ++i)
        #pragma unroll
        for (int j = 0; j < 4; ++j) acc[i][j] = (f32x4){0.f, 0.f, 0.f, 0.f};

    // prologue: fill buffer 0
    gload16(A + gA, &sA[0][lofs]);
    gload16(A + gA + (size_t)16 * K, &sA[0][lofs + 16 * 32]);
    gload16(Bt + gB, &sB[0][lofs]);
    gload16(Bt + gB + (size_t)16 * K, &sB[0][lofs + 16 * 32]);
    __syncthreads();

    int kb = 0;
    for (int k0 = 0; k0 < K; k0 += 32, kb ^= 1) {
        if (k0 + 32 < K) {   // issue next tile BEFORE computing this one
            int nb = kb ^ 1;
            gload16(A + gA + k0 + 32, &sA[nb][lofs]);
            gload16(A + gA + k0 + 32 + (size_t)16 * K, &sA[nb][lofs + 16 * 32]);
            gload16(Bt + gB + k0 + 32, &sB[nb][lofs]);
            gload16(Bt + gB + k0 + 32 + (size_t)16 * K, &sB[nb][lofs + 16 * 32]);
        }

        h8v fa[4], fb[4];
        #pragma unroll
        for (int i = 0; i < 4; ++i) {
            fa[i] = *(const h8v*)&sA[kb][(wm + i * 16 + lm) * 32 + rofs];
            fb[i] = *(const h8v*)&sB[kb][(wn + i * 16 + lm) * 32 + rofs];
        }
        #pragma unroll
        for (int mi = 0; mi < 4; ++mi)
            #pragma unroll
            for (int ni = 0; ni < 4; ++ni)
                acc[mi][ni] = __builtin_amdgcn_mfma_f32_16x16x32_f16(fa[mi], fb[ni], acc[mi][ni], 0, 0, 0);
        __syncthreads();   // drains next-tile DMA; also protects buffer reuse
    }

    // C/D layout: col = lane&15, row = (lane>>4)*4 + reg
    #pragma unroll
    for (int mi = 0; mi < 4; ++mi)
        #pragma unroll
        for (int ni = 0; ni < 4; ++ni) {
            int row = bm + wm + mi * 16 + lq * 4;
            int col = bn + wn + ni * 16 + lm;
            #pragma unroll
            for (int r = 0; r < 4; ++r) {
                float v = acc[mi][ni][r];
                if (EPI == 0) {
                    C[(size_t)(row + r) * ldc + col] = v;
                } else {
                    if (bn < 2048) {
                        H[(size_t)(row + r) * 2048 + col] = (_Float16)v;
                    } else {
                        float s = v / (1.f + __expf(-v));   // silu(res)
                        Hg[(size_t)(row + r) * 2048 + (col - 2048)] = (_Float16)s;
                    }
                }
            }
        }
}

// ---------------------------------------------------------------------------
// Fused x_dbl + delta kernel. Block = 16 rows (grid 256 = 1 block/CU).
// Phase 1 (xd): 4 waves each compute a K=512 partial of xd[16][96]
//   (6 n-frags, direct register A/B loads, no LDS staging), LDS-reduce.
//   Cols 64..79 -> Bm, 80..95 -> Cm (fp32).
// Phase 2 (delta): xd[:, :64] re-read from LDS as MFMA A-operand (2 k-frags),
//   each wave covers 512 of 2048 delta cols: 32 n-frags x 2 MFMA, epilogue
//   softplus(acc + b_dt) -> fp16 delta.
// ---------------------------------------------------------------------------
__global__ __launch_bounds__(256) void xd_delta(const _Float16* __restrict__ xch,
                                                const _Float16* __restrict__ WxT,
                                                const _Float16* __restrict__ WdtT,
                                                const float* __restrict__ b_dt,
                                                _Float16* __restrict__ deltah,
                                                float* __restrict__ Bm,
                                                float* __restrict__ Cm) {
    __shared__ float part[4][16][100];   // row stride 100: 16B-aligned, 2-way banks
    const int tid = threadIdx.x, wave = tid >> 6, lane = tid & 63;
    const int lm = lane & 15, lq = lane >> 4;
    const int m0 = blockIdx.x * 16;
    const int kw = wave * 512;

    f32x4 acc[6];
    #pragma unroll
    for (int i = 0; i < 6; ++i) acc[i] = (f32x4){0.f, 0.f, 0.f, 0.f};

    // A-frag: A[m][k] m=lm, k-chunk=lq*8  -> direct h8v load == frag layout
    const _Float16* aptr = xch + (size_t)(m0 + lm) * D_INNER + kw + lq * 8;
    h8v pa = *(const h8v*)aptr;
    h8v pb[6];
    #pragma unroll
    for (int nf = 0; nf < 6; ++nf)
        pb[nf] = *(const h8v*)(WxT + (size_t)(nf * 16 + lm) * D_INNER + kw + lq * 8);

    for (int s = 0; s < 16; ++s) {
        h8v a = pa;
        h8v b[6];
        #pragma unroll
        for (int nf = 0; nf < 6; ++nf) b[nf] = pb[nf];
        if (s < 15) {
            int kk = (s + 1) * 32;
            pa = *(const h8v*)(aptr + kk);
            #pragma unroll
            for (int nf = 0; nf < 6; ++nf)
                pb[nf] = *(const h8v*)(WxT + (size_t)(nf * 16 + lm) * D_INNER + kw + kk + lq * 8);
        }
        #pragma unroll
        for (int nf = 0; nf < 6; ++nf)
            acc[nf] = __builtin_amdgcn_mfma_f32_16x16x32_f16(a, b[nf], acc[nf], 0, 0, 0);
    }

    // write partials (C-layout: m = lq*4+r, n = nf*16+lm)
    #pragma unroll
    for (int nf = 0; nf < 6; ++nf)
        #pragma unroll
        for (int r = 0; r < 4; ++r)
            part[wave][lq * 4 + r][nf * 16 + lm] = acc[nf][r];
    __syncthreads();

    // reduce 4 partials; scatter B/C; final xd -> part[0]
    for (int e = tid; e < 16 * 96; e += 256) {
        int m = e / 96, n = e - m * 96;
        float v = part[0][m][n] + part[1][m][n] + part[2][m][n] + part[3][m][n];
        if (n >= 64) {
            int row = m0 + m;
            if (n < 80) Bm[(size_t)row * 16 + (n - 64)] = v;
            else        Cm[(size_t)row * 16 + (n - 80)] = v;
        }
        part[0][m][n] = v;
    }
    __syncthreads();

    // phase 2: delta = softplus(xd[:, :64] @ WdtT^T + b_dt)
    h8v af[2];
    #pragma unroll
    for (int kf = 0; kf < 2; ++kf) {
        const float* xp = &part[0][lm][kf * 32 + lq * 8];
        h8v t;
        #pragma unroll
        for (int j = 0; j < 8; ++j) t[j] = (_Float16)xp[j];
        af[kf] = t;
    }
    const int n0w = wave * 512;
    for (int nf = 0; nf < 32; ++nf) {
        int n0 = n0w + nf * 16;
        h8v b0 = *(const h8v*)(WdtT + (size_t)(n0 + lm) * 64 + lq * 8);
        h8v b1 = *(const h8v*)(WdtT + (size_t)(n0 + lm) * 64 + 32 + lq * 8);
        f32x4 a = (f32x4){0.f, 0.f, 0.f, 0.f};
        a = __builtin_amdgcn_mfma_f32_16x16x32_f16(af[0], b0, a, 0, 0, 0);
        a = __builtin_amdgcn_mfma_f32_16x16x32_f16(af[1], b1, a, 0, 0, 0);
        int col = n0 + lm;
        float bd = b_dt[col];
        #pragma unroll
        for (int r = 0; r < 4; ++r) {
            int row = m0 + lq * 4 + r;
            float v = a[r] + bd;
            float sp = (v > 20.f) ? v : log1pf(__expf(v));
            deltah[(size_t)row * D_INNER + col] = (_Float16)sp;
        }
    }
}

// ---------------------------------------------------------------------------
// Depthwise causal conv (k=4) + bias + SiLU, 8 elements/thread.
// ---------------------------------------------------------------------------
__global__ __launch_bounds__(256) void conv_silu(const _Float16* __restrict__ xsh,
                                                 const float* __restrict__ cw,
                                                 const float* __restrict__ cb,
                                                 _Float16* __restrict__ xch) {
    int idx = blockIdx.x * 256 + threadIdx.x;
    int d0 = (idx * 8) & (D_INNER - 1);
    int m  = (idx * 8) >> 11;
    int l  = m & (L_SEQ - 1);
    float acc[8];
    {
        float4 c0 = *(const float4*)&cb[d0];
        float4 c1 = *(const float4*)&cb[d0 + 4];
        acc[0] = c0.x; acc[1] = c0.y; acc[2] = c0.z; acc[3] = c0.w;
        acc[4] = c1.x; acc[5] = c1.y; acc[6] = c1.z; acc[7] = c1.w;
    }
    #pragma unroll
    for (int k = 0; k < 4; ++k) {
        int ll = l - 3 + k;
        if (ll >= 0) {
            h8v v = *(const h8v*)(xsh + (size_t)(m - 3 + k) * D_INNER + d0);
            #pragma unroll
            for (int j = 0; j < 8; ++j)
                acc[j] += (float)v[j] * cw[(d0 + j) * 4 + k];
        }
    }
    h8v o;
    #pragma unroll
    for (int j = 0; j < 8; ++j) {
        float s = acc[j] / (1.f + __expf(-acc[j]));
        o[j] = (_Float16)s;
    }
    *(h8v*)(xch + (size_t)idx * 8) = o;
}

// ---------------------------------------------------------------------------
// Scan pass 1: per (b, chunk, d) chunk-local final state (h0=0) + S=sum(delta).
// ---------------------------------------------------------------------------
__global__ __launch_bounds__(256) void scan_part1(const _Float16* __restrict__ deltah,
                                                  const _Float16* __restrict__ xch,
                                                  const float* __restrict__ Bm,
                                                  const float* __restrict__ A_log,
                                                  float* __restrict__ hlocal,
                                                  float* __restrict__ Ssum) {
    const int t = threadIdx.x;
    const int d = blockIdx.x * 256 + t;
    const int c = blockIdx.y;
    const int b = blockIdx.z;

    float An[16];
    {
        const float4* ap = (const float4*)(A_log + (size_t)d * 16);
        #pragma unroll
        for (int q = 0; q < 4; ++q) {
            float4 v = ap[q];
            An[q * 4 + 0] = -__expf(v.x); An[q * 4 + 1] = -__expf(v.y);
            An[q * 4 + 2] = -__expf(v.z); An[q * 4 + 3] = -__expf(v.w);
        }
    }
    const float An0 = An[0];
    bool fast = An0 < 0.f;
    #pragma unroll
    for (int n = 0; n < 16; ++n)
        fast = fast && (fabsf(An[n] - (float)(n + 1) * An0) < 1e-3f * fabsf(An[n]));

    __shared__ float sB[CLEN][16];
    {
        size_t l0 = (size_t)(b * L_SEQ + c * CLEN) * 16;
        #pragma unroll
        for (int i = 0; i < (CLEN * 16) / 256; ++i) {
            int idx = t + i * 256;
            sB[idx >> 4][idx & 15] = Bm[l0 + idx];
        }
    }
    __syncthreads();

    float h[16];
    #pragma unroll
    for (int n = 0; n < 16; ++n) h[n] = 0.f;
    float S = 0.f;

    size_t base = (size_t)(b * L_SEQ + c * CLEN) * D_INNER + d;
    float bd[PFD], bx[PFD];
    #pragma unroll
    for (int i = 0; i < PFD; ++i) {
        bd[i] = (float)deltah[base + (size_t)i * D_INNER];
        bx[i] = (float)xch[base + (size_t)i * D_INNER];
    }

    if (fast) {
        for (int jb = 0; jb < CLEN; jb += PFD) {
            #pragma unroll
            for (int i = 0; i < PFD; ++i) {
                int j = jb + i;
                float dv = bd[i], xv = bx[i];
                int jn = j + PFD;
                if (jn < CLEN) {
                    bd[i] = (float)deltah[base + (size_t)jn * D_INNER];
                    bx[i] = (float)xch[base + (size_t)jn * D_INNER];
                }
                S += dv;
                float dbx = dv * xv;
                float r = __expf(dv * An0);
                float pw = r;
                #pragma unroll
                for (int n = 0; n < 16; ++n) {
                    h[n] = pw * h[n] + dbx * sB[j][n];
                    pw *= r;
                }
            }
        }
    } else {
        for (int jb = 0; jb < CLEN; jb += PFD) {
            #pragma unroll
            for (int i = 0; i < PFD; ++i) {
                int j = jb + i;
                float dv = bd[i], xv = bx[i];
                int jn = j + PFD;
                if (jn < CLEN) {
                    bd[i] = (float)deltah[base + (size_t)jn * D_INNER];
                    bx[i] = (float)xch[base + (size_t)jn * D_INNER];
                }
                S += dv;
                float dbx = dv * xv;
                #pragma unroll
                for (int n = 0; n < 16; ++n)
                    h[n] = __expf(dv * An[n]) * h[n] + dbx * sB[j][n];
            }
        }
    }

    size_t o = ((size_t)(b * NCH + c) * D_INNER + d) * 16;
    float4* hp = (float4*)(hlocal + o);
    #pragma unroll
    for (int q = 0; q < 4; ++q)
        hp[q] = make_float4(h[q * 4], h[q * 4 + 1], h[q * 4 + 2], h[q * 4 + 3]);
    Ssum[(size_t)(b * NCH + c) * D_INNER + d] = S;
}

// ---------------------------------------------------------------------------
// Combine: sequential over NCH chunks per (b,d,n); writes each chunk's h0.
// ---------------------------------------------------------------------------
__global__ __launch_bounds__(256) void scan_combine(const float* __restrict__ hlocal,
                                                    const float* __restrict__ Ssum,
                                                    const float* __restrict__ A_log,
                                                    float* __restrict__ h0buf) {
    int gid = blockIdx.x * 256 + threadIdx.x;
    int n = gid & 15;
    int d = (gid >> 4) & (D_INNER - 1);
    int b = gid >> 15;
    float An = -__expf(A_log[(size_t)d * 16 + n]);
    float H = 0.f;
    float pS[4], pH[4];
    #pragma unroll
    for (int i = 0; i < 4; ++i) {
        size_t sc = (size_t)(b * NCH + i) * D_INNER + d;
        pS[i] = Ssum[sc];
        pH[i] = hlocal[sc * 16 + n];
    }
    for (int cb = 0; cb < NCH; cb += 4) {
        #pragma unroll
        for (int i = 0; i < 4; ++i) {
            int c = cb + i;
            float S = pS[i], hl = pH[i];
            int cn = c + 4;
            if (cn < NCH) {
                size_t sc = (size_t)(b * NCH + cn) * D_INNER + d;
                pS[i] = Ssum[sc];
                pH[i] = hlocal[sc * 16 + n];
            }
            size_t o = ((size_t)(b * NCH + c) * D_INNER + d) * 16 + n;
            h0buf[o] = H;
            H = __expf(An * S) * H + hl;
        }
    }
}

// ---------------------------------------------------------------------------
// Scan pass 2: replay from h0; y = sum_n h*C; fuse +xc*D and *pre-silu'd gate;
// write y fp16 (A-operand of the output GEMM).
// ---------------------------------------------------------------------------
__global__ __launch_bounds__(256) void scan_part2(const _Float16* __restrict__ deltah,
                                                  const _Float16* __restrict__ xch,
                                                  const float* __restrict__ Bm,
                                                  const float* __restrict__ Cm,
                                                  const float* __restrict__ h0buf,
                                                  const float* __restrict__ A_log,
                                                  const float* __restrict__ Dp,
                                                  const _Float16* __restrict__ sresh,
                                                  _Float16* __restrict__ yhalf) {
    const int t = threadIdx.x;
    const int d = blockIdx.x * 256 + t;
    const int c = blockIdx.y;
    const int b = blockIdx.z;

    float An[16];
    {
        const float4* ap = (const float4*)(A_log + (size_t)d * 16);
        #pragma unroll
        for (int q = 0; q < 4; ++q) {
            float4 v = ap[q];
            An[q * 4 + 0] = -__expf(v.x); An[q * 4 + 1] = -__expf(v.y);
            An[q * 4 + 2] = -__expf(v.z); An[q * 4 + 3] = -__expf(v.w);
        }
    }
    const float An0 = An[0];
    bool fast = An0 < 0.f;
    #pragma unroll
    for (int n = 0; n < 16; ++n)
        fast = fast && (fabsf(An[n] - (float)(n + 1) * An0) < 1e-3f * fabsf(An[n]));

    __shared__ float sB[CLEN][16];
    __shared__ float sC[CLEN][16];
    {
        size_t l0 = (size_t)(b * L_SEQ + c * CLEN) * 16;
        #pragma unroll
        for (int i = 0; i < (CLEN * 16) / 256; ++i) {
            int idx = t + i * 256;
            sB[idx >> 4][idx & 15] = Bm[l0 + idx];
            sC[idx >> 4][idx & 15] = Cm[l0 + idx];
        }
    }
    __syncthreads();

    float h[16];
    {
        size_t o = ((size_t)(b * NCH + c) * D_INNER + d) * 16;
        const float4* hp = (const float4*)(h0buf + o);
        #pragma unroll
        for (int q = 0; q < 4; ++q) {
            float4 v = hp[q];
            h[q * 4 + 0] = v.x; h[q * 4 + 1] = v.y;
            h[q * 4 + 2] = v.z; h[q * 4 + 3] = v.w;
        }
    }
    const float Dv = Dp[d];

    size_t base = (size_t)(b * L_SEQ + c * CLEN) * D_INNER + d;
    float bd[PFD], bx[PFD], bg[PFD];
    #pragma unroll
    for (int i = 0; i < PFD; ++i) {
        bd[i] = (float)deltah[base + (size_t)i * D_INNER];
        bx[i] = (float)xch[base + (size_t)i * D_INNER];
        bg[i] = (float)sresh[base + (size_t)i * D_INNER];
    }

    if (fast) {
        for (int jb = 0; jb < CLEN; jb += PFD) {
            #pragma unroll
            for (int i = 0; i < PFD; ++i) {
                int j = jb + i;
                float dv = bd[i], xv = bx[i], gv = bg[i];
                int jn = j + PFD;
                if (jn < CLEN) {
                    bd[i] = (float)deltah[base + (size_t)jn * D_INNER];
                    bx[i] = (float)xch[base + (size_t)jn * D_INNER];
                    bg[i] = (float)sresh[base + (size_t)jn * D_INNER];
                }
                float dbx = dv * xv;
                float r = __expf(dv * An0);
                float pw = r;
                float y = 0.f;
                #pragma unroll
                for (int n = 0; n < 16; ++n) {
                    h[n] = pw * h[n] + dbx * sB[j][n];
                    y += h[n] * sC[j][n];
                    pw *= r;
                }
                float yv = (y + xv * Dv) * gv;
                yhalf[base + (size_t)j * D_INNER] = (_Float16)yv;
            }
        }
    } else {
        for (int jb = 0; jb < CLEN; jb += PFD) {
            #pragma unroll
            for (int i = 0; i < PFD; ++i) {
                int j = jb + i;
                float dv = bd[i], xv = bx[i], gv = bg[i];
                int jn = j + PFD;
                if (jn < CLEN) {
                    bd[i] = (float)deltah[base + (size_t)jn * D_INNER];
                    bx[i] = (float)xch[base + (size_t)jn * D_INNER];
                    bg[i] = (float)sresh[base + (size_t)jn * D_INNER];
                }
                float dbx = dv * xv;
                float y = 0.f;
                #pragma unroll
                for (int n = 0; n < 16; ++n) {
                    h[n] = __expf(dv * An[n]) * h[n] + dbx * sB[j][n];
                    y += h[n] * sC[j][n];
                }
                float yv = (y + xv * Dv) * gv;
                yhalf[base + (size_t)j * D_INNER] = (_Float16)yv;
            }
        }
    }
}

extern "C" void kernel_launch(void* const* d_in, const int* in_sizes, int n_in,
                              void* d_out, int out_size, void* d_ws, size_t ws_size,
                              hipStream_t stream) {
    const float* x      = (const float*)d_in[0];
    const float* W_in   = (const float*)d_in[1];
    const float* conv_w = (const float*)d_in[2];
    const float* conv_b = (const float*)d_in[3];
    const float* W_x    = (const float*)d_in[4];
    const float* W_dt   = (const float*)d_in[5];
    const float* b_dt   = (const float*)d_in[6];
    const float* A_log  = (const float*)d_in[7];
    const float* D_par  = (const float*)d_in[8];
    const float* W_out  = (const float*)d_in[9];
    float* out = (float*)d_out;

    char* wsb = (char*)d_ws;
    _Float16*  xsh    = (_Float16*)(wsb + 0);             // 16,777,216 B
    _Float16*  sresh  = (_Float16*)(wsb + 16777216);      // 16,777,216 B
    _Float16*  deltah = (_Float16*)(wsb + 33554432);      // 16,777,216 B
    _Float16*  xch    = (_Float16*)(wsb + 50331648);      // 16,777,216 B
    _Float16*  xf16   = (_Float16*)(wsb + 67108864);      //  8,388,608 B (dead after K1)
    _Float16*  WinT   = (_Float16*)(wsb + 75497472);      //  8,388,608 B (dead after K1)
    _Float16*  yhalf  = (_Float16*)(wsb + 67108864);      // 16,777,216 B (aliases xf16+WinT)
    _Float16*  WxT    = (_Float16*)(wsb + 83886080);      //    393,216 B
    _Float16*  WdtT   = (_Float16*)(wsb + 84279296);      //    262,144 B
    float*     Bbuf   = (float*)(wsb + 84541440);         //    262,144 B
    float*     Cbuf   = (float*)(wsb + 84803584);         //    262,144 B
    float*     Ssum   = (float*)(wsb + 85065728);         //  1,048,576 B
    float*     hloc   = (float*)(wsb + 86114304);         // 16,777,216 B
    float*     h0buf  = (float*)(wsb + 102891520);        // 16,777,216 B
    _Float16*  WoutT  = (_Float16*)(wsb + 119668736);     //  4,194,304 B
    // end: 123,863,040 B

    dim3 blk(256);

    // 1. fused prep: all weight transposes + x cast
    prep<<<dim3(10560), blk, 0, stream>>>(x, xf16, W_in, WinT, W_x, WxT,
                                          W_dt, WdtT, W_out, WoutT);
    // 2. K1: [xs fp16 | silu(res) fp16] = x @ W_in  (M=4096, N=4096, K=1024)
    gemm_f16<2><<<dim3(32, 32), blk, 0, stream>>>(
        xf16, WinT, nullptr, xsh, sresh, MM, 2 * D_INNER, D_MODEL, 2048);
    // 3. conv + SiLU -> xch fp16
    conv_silu<<<dim3((size_t)MM * D_INNER / 8 / 256), blk, 0, stream>>>(xsh, conv_w, conv_b, xch);
    // 4. fused xd + delta (B, C fp32; delta fp16)
    xd_delta<<<dim3(MM / 16), blk, 0, stream>>>(xch, WxT, WdtT, b_dt, deltah, Bbuf, Cbuf);
    // 5. scan pass 1
    scan_part1<<<dim3(D_INNER / 256, NCH, B_SZ), blk, 0, stream>>>(deltah, xch, Bbuf, A_log, hloc, Ssum);
    // 6. combine
    scan_combine<<<dim3(B_SZ * D_INNER * 16 / 256), blk, 0, stream>>>(hloc, Ssum, A_log, h0buf);
    // 7. scan pass 2 (+gating) -> yhalf fp16
    scan_part2<<<dim3(D_INNER / 256, NCH, B_SZ), blk, 0, stream>>>(deltah, xch, Bbuf, Cbuf, h0buf, A_log, D_par, sresh, yhalf);
    // 8. K5: out = y @ W_out  (M=4096, N=1024, K=2048)
    gemm_f16<0><<<dim3(8, 32), blk, 0, stream>>>(
        yhalf, WoutT, out, nullptr, nullptr, MM, D_MODEL, D_INNER, D_MODEL);
}

// Round 9
// 367.989 us; speedup vs baseline: 1.0575x; 1.0575x over previous
//
#include <hip/hip_runtime.h>
#include <math.h>

#define B_SZ    2
#define L_SEQ   2048
#define D_MODEL 1024
#define D_INNER 2048
#define D_STATE 16
#define DT_RANK 64
#define MM      (B_SZ * L_SEQ)   // 4096 rows
#define NCH     64               // scan chunks
#define CLEN    (L_SEQ / NCH)    // 32 steps per chunk
#define PFD     8                // scan prefetch depth

typedef _Float16 h8v __attribute__((ext_vector_type(8)));
typedef _Float16 h4v __attribute__((ext_vector_type(4)));
typedef float f32x4 __attribute__((ext_vector_type(4)));

// Async global->LDS DMA, 16B per lane. LDS dest = uniform base + lane*16.
__device__ __forceinline__ void gload16(const void* g, void* l) {
    __builtin_amdgcn_global_load_lds((const __attribute__((address_space(1))) void*)g,
                                     (__attribute__((address_space(3))) void*)l, 16, 0, 0);
}

// ---------------------------------------------------------------------------
// prep: all weight transposes (fp32 -> fp16 T[N][K]) + x -> fp16 cast.
// ---------------------------------------------------------------------------
__global__ __launch_bounds__(256) void prep(const float* __restrict__ x,
                                            _Float16* __restrict__ xf16,
                                            const float* __restrict__ W_in,
                                            _Float16* __restrict__ WinT,
                                            const float* __restrict__ W_x,
                                            _Float16* __restrict__ WxT,
                                            const float* __restrict__ W_dt,
                                            _Float16* __restrict__ WdtT,
                                            const float* __restrict__ W_out,
                                            _Float16* __restrict__ WoutT) {
    __shared__ float t[32][33];
    const int b = blockIdx.x;
    const float* W; _Float16* T; int K, N, tile;
    if (b < 4096)      { W = W_in;  T = WinT;  K = 1024; N = 4096; tile = b; }
    else if (b < 4288) { W = W_x;   T = WxT;   K = 2048; N = 96;   tile = b - 4096; }
    else if (b < 4416) { W = W_dt;  T = WdtT;  K = 64;   N = 2048; tile = b - 4288; }
    else if (b < 6464) { W = W_out; T = WoutT; K = 2048; N = 1024; tile = b - 4416; }
    else {
        int idx = (b - 6464) * 256 + threadIdx.x;
        float4 v = ((const float4*)x)[idx];
        h4v h = {(_Float16)v.x, (_Float16)v.y, (_Float16)v.z, (_Float16)v.w};
        *(h4v*)(xf16 + (size_t)idx * 4) = h;
        return;
    }
    const int ntx = N / 32;
    const int k0 = (tile / ntx) * 32, n0 = (tile % ntx) * 32;
    #pragma unroll
    for (int i = 0; i < 4; ++i) {
        int idx = threadIdx.x + i * 256;
        int r = idx >> 5, c = idx & 31;
        t[r][c] = W[(size_t)(k0 + r) * N + n0 + c];
    }
    __syncthreads();
    #pragma unroll
    for (int i = 0; i < 4; ++i) {
        int idx = threadIdx.x + i * 256;
        int n = idx >> 5, k = idx & 31;
        T[(size_t)(n0 + n) * K + k0 + k] = (_Float16)t[k][n];
    }
}

// ---------------------------------------------------------------------------
// fp16 MFMA GEMM, double-buffered async DMA: C = A[M][K] @ Bt[N][K]^T.
// 128x128 tile, 256 thr, 4 waves 2x2, wave 64x64 (4x4 16x16x32 frags), BK=32.
// K-loop: issue DMA(k+1) -> MFMA(k) -> barrier.
// Buffer offsets computed arithmetically (NO pointer arrays -- LDS pointers
// in an initialized array trip an addrspacecast static-initializer error).
// Epilogue: per-wave LDS transpose -> vectorized 16B stores.
// EPI 0: fp32 C. EPI 1: fp16 H = softplus(acc+bias[col]).
// EPI 2: bn<2048 -> fp16 H (xs); bn>=2048 -> silu -> fp16 Hg (gate).
// ---------------------------------------------------------------------------
template<int EPI>
__global__ __launch_bounds__(256) void gemm_f16(const _Float16* __restrict__ A,
                                                const _Float16* __restrict__ Bt,
                                                const float* __restrict__ bias,
                                                float* __restrict__ C,
                                                _Float16* __restrict__ H,
                                                _Float16* __restrict__ Hg,
                                                int M, int N, int K, int ldc) {
    __shared__ _Float16 smemh[16384];   // 32KB: staging dbuf, reused by epilogue

    const int tid = threadIdx.x;
    const int wave = tid >> 6, lane = tid & 63;
    const int bm = blockIdx.y * 128, bn = blockIdx.x * 128;

    const int lrow = lane >> 2, pc = lane & 3;
    const int ar = wave * 32 + lrow;
    const size_t gA = (size_t)(bm + ar) * K + ((pc ^ ((ar >> 1) & 3)) * 8);
    const size_t gB = (size_t)(bn + ar) * K + ((pc ^ ((ar >> 1) & 3)) * 8);
    const int lofs = (wave * 32) * 32;

    const int lm = lane & 15, lq = lane >> 4;
    const int rofs = (lq ^ ((lm >> 1) & 3)) * 8;
    const int wm = (wave >> 1) * 64, wn = (wave & 1) * 64;

    f32x4 acc[4][4];
    #pragma unroll
    for (int i = 0; i < 4; ++i)
        #pragma unroll
        for (int j = 0; j < 4; ++j) acc[i][j] = (f32x4){0.f, 0.f, 0.f, 0.f};

    // prologue: fill buffer 0  (A buf at kb*4096, B buf at 8192 + kb*4096)
    gload16(A + gA, smemh + lofs);
    gload16(A + gA + (size_t)16 * K, smemh + lofs + 16 * 32);
    gload16(Bt + gB, smemh + 8192 + lofs);
    gload16(Bt + gB + (size_t)16 * K, smemh + 8192 + lofs + 16 * 32);
    __syncthreads();

    int kb = 0;
    for (int k0 = 0; k0 < K; k0 += 32, kb ^= 1) {
        if (k0 + 32 < K) {   // issue next tile BEFORE computing this one
            int nb = kb ^ 1;
            gload16(A + gA + k0 + 32, smemh + nb * 4096 + lofs);
            gload16(A + gA + k0 + 32 + (size_t)16 * K, smemh + nb * 4096 + lofs + 16 * 32);
            gload16(Bt + gB + k0 + 32, smemh + 8192 + nb * 4096 + lofs);
            gload16(Bt + gB + k0 + 32 + (size_t)16 * K, smemh + 8192 + nb * 4096 + lofs + 16 * 32);
        }

        const _Float16* sA = smemh + kb * 4096;
        const _Float16* sB = smemh + 8192 + kb * 4096;
        h8v fa[4], fb[4];
        #pragma unroll
        for (int i = 0; i < 4; ++i) {
            fa[i] = *(const h8v*)&sA[(wm + i * 16 + lm) * 32 + rofs];
            fb[i] = *(const h8v*)&sB[(wn + i * 16 + lm) * 32 + rofs];
        }
        #pragma unroll
        for (int mi = 0; mi < 4; ++mi)
            #pragma unroll
            for (int ni = 0; ni < 4; ++ni)
                acc[mi][ni] = __builtin_amdgcn_mfma_f32_16x16x32_f16(fa[mi], fb[ni], acc[mi][ni], 0, 0, 0);
        __syncthreads();   // drains next-tile DMA; protects buffer reuse
    }
    // after final barrier all waves are done with staging LDS -> reuse it.

    if (EPI == 0) {
        float* ep = (float*)smemh + wave * 1088;   // 16 x 68 fp32 (padded)
        #pragma unroll
        for (int mi = 0; mi < 4; ++mi) {
            #pragma unroll
            for (int ni = 0; ni < 4; ++ni)
                #pragma unroll
                for (int r = 0; r < 4; ++r)
                    ep[(lq * 4 + r) * 68 + ni * 16 + lm] = acc[mi][ni][r];
            int rowb = bm + wm + mi * 16;
            #pragma unroll
            for (int i = 0; i < 4; ++i) {
                int ch = lane + 64 * i;
                int row = ch >> 4, c4 = (ch & 15) * 4;
                *(float4*)&C[(size_t)(rowb + row) * ldc + bn + wn + c4] =
                    *(const float4*)&ep[row * 68 + c4];
            }
        }
    } else {
        _Float16* ep = smemh + wave * 1152;        // 16 x 72 fp16 (padded, 16B rows)
        const bool gate = (EPI == 2) && (bn >= 2048);
        _Float16* dst = gate ? Hg : H;
        const int cb = bn + wn - (gate ? 2048 : 0);
        #pragma unroll
        for (int mi = 0; mi < 4; ++mi) {
            #pragma unroll
            for (int ni = 0; ni < 4; ++ni) {
                int col = bn + wn + ni * 16 + lm;
                #pragma unroll
                for (int r = 0; r < 4; ++r) {
                    float v = acc[mi][ni][r];
                    if (EPI == 1) {
                        float a = v + bias[col];
                        v = (a > 20.f) ? a : log1pf(__expf(a));
                    } else if (gate) {
                        v = v / (1.f + __expf(-v));
                    }
                    ep[(lq * 4 + r) * 72 + ni * 16 + lm] = (_Float16)v;
                }
            }
            int rowb = bm + wm + mi * 16;
            #pragma unroll
            for (int i = 0; i < 2; ++i) {
                int ch = lane + 64 * i;
                int row = ch >> 3, c8 = (ch & 7) * 8;
                *(h8v*)&dst[(size_t)(rowb + row) * ldc + cb + c8] =
                    *(const h8v*)&ep[row * 72 + c8];
            }
        }
    }
}

// ---------------------------------------------------------------------------
// Skinny fp16 MFMA GEMM for x_dbl: xd[4096][96] = xch @ WxT^T. 64 rows/block,
// 4 waves x 16 rows x 96 cols. LDS-staged register-prefetch (proven R5/R6).
// Epilogue scatters: 0..63 -> xdh fp16, 64..79 -> Bm, 80..95 -> Cm.
// ---------------------------------------------------------------------------
__global__ __launch_bounds__(256) void gemm_xd(const _Float16* __restrict__ xch,
                                               const _Float16* __restrict__ WxT,
                                               _Float16* __restrict__ xdh,
                                               float* __restrict__ Bm,
                                               float* __restrict__ Cm) {
    __shared__ _Float16 sA[64 * 32];
    __shared__ _Float16 sB[96 * 32];
    const int tid = threadIdx.x;
    const int m0 = blockIdx.x * 64;
    const int wave = tid >> 6, lane = tid & 63;
    const int lm = lane & 15, lq = lane >> 4;
    const int rofs = (lq ^ ((lm >> 1) & 3)) * 8;

    const int wr = tid >> 2, wc = tid & 3, c0 = wc * 8;
    const int wofsA = wr * 32 + ((wc ^ ((wr >> 1) & 3)) * 8);
    const int wr2 = 64 + wr;
    const int wofsB2 = wr2 * 32 + ((wc ^ ((wr2 >> 1) & 3)) * 8);

    f32x4 acc[6];
    #pragma unroll
    for (int i = 0; i < 6; ++i) acc[i] = (f32x4){0.f, 0.f, 0.f, 0.f};

    h8v pA = *(const h8v*)(xch + (size_t)(m0 + wr) * D_INNER + c0);
    h8v pB0 = *(const h8v*)(WxT + (size_t)wr * D_INNER + c0);
    h8v pB1 = (tid < 128) ? *(const h8v*)(WxT + (size_t)wr2 * D_INNER + c0) : (h8v)0;

    for (int k0 = 0; k0 < D_INNER; k0 += 32) {
        *(h8v*)&sA[wofsA] = pA;
        *(h8v*)&sB[wofsA] = pB0;
        if (tid < 128) *(h8v*)&sB[wofsB2] = pB1;
        __syncthreads();

        if (k0 + 32 < D_INNER) {
            int kk = k0 + 32 + c0;
            pA = *(const h8v*)(xch + (size_t)(m0 + wr) * D_INNER + kk);
            pB0 = *(const h8v*)(WxT + (size_t)wr * D_INNER + kk);
            if (tid < 128) pB1 = *(const h8v*)(WxT + (size_t)wr2 * D_INNER + kk);
        }

        h8v fa = *(const h8v*)&sA[(wave * 16 + lm) * 32 + rofs];
        #pragma unroll
        for (int nf = 0; nf < 6; ++nf) {
            h8v fb = *(const h8v*)&sB[(nf * 16 + lm) * 32 + rofs];
            acc[nf] = __builtin_amdgcn_mfma_f32_16x16x32_f16(fa, fb, acc[nf], 0, 0, 0);
        }
        __syncthreads();
    }

    #pragma unroll
    for (int nf = 0; nf < 6; ++nf) {
        int col = nf * 16 + lm;
        #pragma unroll
        for (int r = 0; r < 4; ++r) {
            int row = m0 + wave * 16 + lq * 4 + r;
            float v = acc[nf][r];
            if (col < 64)      xdh[(size_t)row * 64 + col] = (_Float16)v;
            else if (col < 80) Bm[(size_t)row * 16 + (col - 64)] = v;
            else               Cm[(size_t)row * 16 + (col - 80)] = v;
        }
    }
}

// ---------------------------------------------------------------------------
// Depthwise causal conv (k=4) + bias + SiLU, 8 elements/thread.
// ---------------------------------------------------------------------------
__global__ __launch_bounds__(256) void conv_silu(const _Float16* __restrict__ xsh,
                                                 const float* __restrict__ cw,
                                                 const float* __restrict__ cb,
                                                 _Float16* __restrict__ xch) {
    int idx = blockIdx.x * 256 + threadIdx.x;
    int d0 = (idx * 8) & (D_INNER - 1);
    int m  = (idx * 8) >> 11;
    int l  = m & (L_SEQ - 1);
    float acc[8];
    {
        float4 c0 = *(const float4*)&cb[d0];
        float4 c1 = *(const float4*)&cb[d0 + 4];
        acc[0] = c0.x; acc[1] = c0.y; acc[2] = c0.z; acc[3] = c0.w;
        acc[4] = c1.x; acc[5] = c1.y; acc[6] = c1.z; acc[7] = c1.w;
    }
    #pragma unroll
    for (int k = 0; k < 4; ++k) {
        int ll = l - 3 + k;
        if (ll >= 0) {
            h8v v = *(const h8v*)(xsh + (size_t)(m - 3 + k) * D_INNER + d0);
            #pragma unroll
            for (int j = 0; j < 8; ++j)
                acc[j] += (float)v[j] * cw[(d0 + j) * 4 + k];
        }
    }
    h8v o;
    #pragma unroll
    for (int j = 0; j < 8; ++j) {
        float s = acc[j] / (1.f + __expf(-acc[j]));
        o[j] = (_Float16)s;
    }
    *(h8v*)(xch + (size_t)idx * 8) = o;
}

// ---------------------------------------------------------------------------
// Scan pass 1: per (b, chunk, d) chunk-local final state (h0=0) + S=sum(delta).
// ---------------------------------------------------------------------------
__global__ __launch_bounds__(256) void scan_part1(const _Float16* __restrict__ deltah,
                                                  const _Float16* __restrict__ xch,
                                                  const float* __restrict__ Bm,
                                                  const float* __restrict__ A_log,
                                                  float* __restrict__ hlocal,
                                                  float* __restrict__ Ssum) {
    const int t = threadIdx.x;
    const int d = blockIdx.x * 256 + t;
    const int c = blockIdx.y;
    const int b = blockIdx.z;

    float An[16];
    {
        const float4* ap = (const float4*)(A_log + (size_t)d * 16);
        #pragma unroll
        for (int q = 0; q < 4; ++q) {
            float4 v = ap[q];
            An[q * 4 + 0] = -__expf(v.x); An[q * 4 + 1] = -__expf(v.y);
            An[q * 4 + 2] = -__expf(v.z); An[q * 4 + 3] = -__expf(v.w);
        }
    }
    const float An0 = An[0];
    bool fast = An0 < 0.f;
    #pragma unroll
    for (int n = 0; n < 16; ++n)
        fast = fast && (fabsf(An[n] - (float)(n + 1) * An0) < 1e-3f * fabsf(An[n]));

    __shared__ float sB[CLEN][16];
    {
        size_t l0 = (size_t)(b * L_SEQ + c * CLEN) * 16;
        #pragma unroll
        for (int i = 0; i < (CLEN * 16) / 256; ++i) {
            int idx = t + i * 256;
            sB[idx >> 4][idx & 15] = Bm[l0 + idx];
        }
    }
    __syncthreads();

    float h[16];
    #pragma unroll
    for (int n = 0; n < 16; ++n) h[n] = 0.f;
    float S = 0.f;

    size_t base = (size_t)(b * L_SEQ + c * CLEN) * D_INNER + d;
    float bd[PFD], bx[PFD];
    #pragma unroll
    for (int i = 0; i < PFD; ++i) {
        bd[i] = (float)deltah[base + (size_t)i * D_INNER];
        bx[i] = (float)xch[base + (size_t)i * D_INNER];
    }

    if (fast) {
        for (int jb = 0; jb < CLEN; jb += PFD) {
            #pragma unroll
            for (int i = 0; i < PFD; ++i) {
                int j = jb + i;
                float dv = bd[i], xv = bx[i];
                int jn = j + PFD;
                if (jn < CLEN) {
                    bd[i] = (float)deltah[base + (size_t)jn * D_INNER];
                    bx[i] = (float)xch[base + (size_t)jn * D_INNER];
                }
                S += dv;
                float dbx = dv * xv;
                float r = __expf(dv * An0);
                float pw = r;
                #pragma unroll
                for (int n = 0; n < 16; ++n) {
                    h[n] = pw * h[n] + dbx * sB[j][n];
                    pw *= r;
                }
            }
        }
    } else {
        for (int jb = 0; jb < CLEN; jb += PFD) {
            #pragma unroll
            for (int i = 0; i < PFD; ++i) {
                int j = jb + i;
                float dv = bd[i], xv = bx[i];
                int jn = j + PFD;
                if (jn < CLEN) {
                    bd[i] = (float)deltah[base + (size_t)jn * D_INNER];
                    bx[i] = (float)xch[base + (size_t)jn * D_INNER];
                }
                S += dv;
                float dbx = dv * xv;
                #pragma unroll
                for (int n = 0; n < 16; ++n)
                    h[n] = __expf(dv * An[n]) * h[n] + dbx * sB[j][n];
            }
        }
    }

    size_t o = ((size_t)(b * NCH + c) * D_INNER + d) * 16;
    float4* hp = (float4*)(hlocal + o);
    #pragma unroll
    for (int q = 0; q < 4; ++q)
        hp[q] = make_float4(h[q * 4], h[q * 4 + 1], h[q * 4 + 2], h[q * 4 + 3]);
    Ssum[(size_t)(b * NCH + c) * D_INNER + d] = S;
}

// ---------------------------------------------------------------------------
// Combine: sequential over NCH chunks per (b,d,n); writes each chunk's h0.
// ---------------------------------------------------------------------------
__global__ __launch_bounds__(256) void scan_combine(const float* __restrict__ hlocal,
                                                    const float* __restrict__ Ssum,
                                                    const float* __restrict__ A_log,
                                                    float* __restrict__ h0buf) {
    int gid = blockIdx.x * 256 + threadIdx.x;
    int n = gid & 15;
    int d = (gid >> 4) & (D_INNER - 1);
    int b = gid >> 15;
    float An = -__expf(A_log[(size_t)d * 16 + n]);
    float H = 0.f;
    float pS[4], pH[4];
    #pragma unroll
    for (int i = 0; i < 4; ++i) {
        size_t sc = (size_t)(b * NCH + i) * D_INNER + d;
        pS[i] = Ssum[sc];
        pH[i] = hlocal[sc * 16 + n];
    }
    for (int cb = 0; cb < NCH; cb += 4) {
        #pragma unroll
        for (int i = 0; i < 4; ++i) {
            int c = cb + i;
            float S = pS[i], hl = pH[i];
            int cn = c + 4;
            if (cn < NCH) {
                size_t sc = (size_t)(b * NCH + cn) * D_INNER + d;
                pS[i] = Ssum[sc];
                pH[i] = hlocal[sc * 16 + n];
            }
            size_t o = ((size_t)(b * NCH + c) * D_INNER + d) * 16 + n;
            h0buf[o] = H;
            H = __expf(An * S) * H + hl;
        }
    }
}

// ---------------------------------------------------------------------------
// Scan pass 2: replay from h0; y = sum_n h*C; fuse +xc*D and *pre-silu'd gate;
// write y fp16 (A-operand of the output GEMM).
// ---------------------------------------------------------------------------
__global__ __launch_bounds__(256) void scan_part2(const _Float16* __restrict__ deltah,
                                                  const _Float16* __restrict__ xch,
                                                  const float* __restrict__ Bm,
                                                  const float* __restrict__ Cm,
                                                  const float* __restrict__ h0buf,
                                                  const float* __restrict__ A_log,
                                                  const float* __restrict__ Dp,
                                                  const _Float16* __restrict__ sresh,
                                                  _Float16* __restrict__ yhalf) {
    const int t = threadIdx.x;
    const int d = blockIdx.x * 256 + t;
    const int c = blockIdx.y;
    const int b = blockIdx.z;

    float An[16];
    {
        const float4* ap = (const float4*)(A_log + (size_t)d * 16);
        #pragma unroll
        for (int q = 0; q < 4; ++q) {
            float4 v = ap[q];
            An[q * 4 + 0] = -__expf(v.x); An[q * 4 + 1] = -__expf(v.y);
            An[q * 4 + 2] = -__expf(v.z); An[q * 4 + 3] = -__expf(v.w);
        }
    }
    const float An0 = An[0];
    bool fast = An0 < 0.f;
    #pragma unroll
    for (int n = 0; n < 16; ++n)
        fast = fast && (fabsf(An[n] - (float)(n + 1) * An0) < 1e-3f * fabsf(An[n]));

    __shared__ float sB[CLEN][16];
    __shared__ float sC[CLEN][16];
    {
        size_t l0 = (size_t)(b * L_SEQ + c * CLEN) * 16;
        #pragma unroll
        for (int i = 0; i < (CLEN * 16) / 256; ++i) {
            int idx = t + i * 256;
            sB[idx >> 4][idx & 15] = Bm[l0 + idx];
            sC[idx >> 4][idx & 15] = Cm[l0 + idx];
        }
    }
    __syncthreads();

    float h[16];
    {
        size_t o = ((size_t)(b * NCH + c) * D_INNER + d) * 16;
        const float4* hp = (const float4*)(h0buf + o);
        #pragma unroll
        for (int q = 0; q < 4; ++q) {
            float4 v = hp[q];
            h[q * 4 + 0] = v.x; h[q * 4 + 1] = v.y;
            h[q * 4 + 2] = v.z; h[q * 4 + 3] = v.w;
        }
    }
    const float Dv = Dp[d];

    size_t base = (size_t)(b * L_SEQ + c * CLEN) * D_INNER + d;
    float bd[PFD], bx[PFD], bg[PFD];
    #pragma unroll
    for (int i = 0; i < PFD; ++i) {
        bd[i] = (float)deltah[base + (size_t)i * D_INNER];
        bx[i] = (float)xch[base + (size_t)i * D_INNER];
        bg[i] = (float)sresh[base + (size_t)i * D_INNER];
    }

    if (fast) {
        for (int jb = 0; jb < CLEN; jb += PFD) {
            #pragma unroll
            for (int i = 0; i < PFD; ++i) {
                int j = jb + i;
                float dv = bd[i], xv = bx[i], gv = bg[i];
                int jn = j + PFD;
                if (jn < CLEN) {
                    bd[i] = (float)deltah[base + (size_t)jn * D_INNER];
                    bx[i] = (float)xch[base + (size_t)jn * D_INNER];
                    bg[i] = (float)sresh[base + (size_t)jn * D_INNER];
                }
                float dbx = dv * xv;
                float r = __expf(dv * An0);
                float pw = r;
                float y = 0.f;
                #pragma unroll
                for (int n = 0; n < 16; ++n) {
                    h[n] = pw * h[n] + dbx * sB[j][n];
                    y += h[n] * sC[j][n];
                    pw *= r;
                }
                float yv = (y + xv * Dv) * gv;
                yhalf[base + (size_t)j * D_INNER] = (_Float16)yv;
            }
        }
    } else {
        for (int jb = 0; jb < CLEN; jb += PFD) {
            #pragma unroll
            for (int i = 0; i < PFD; ++i) {
                int j = jb + i;
                float dv = bd[i], xv = bx[i], gv = bg[i];
                int jn = j + PFD;
                if (jn < CLEN) {
                    bd[i] = (float)deltah[base + (size_t)jn * D_INNER];
                    bx[i] = (float)xch[base + (size_t)jn * D_INNER];
                    bg[i] = (float)sresh[base + (size_t)jn * D_INNER];
                }
                float dbx = dv * xv;
                float y = 0.f;
                #pragma unroll
                for (int n = 0; n < 16; ++n) {
                    h[n] = __expf(dv * An[n]) * h[n] + dbx * sB[j][n];
                    y += h[n] * sC[j][n];
                }
                float yv = (y + xv * Dv) * gv;
                yhalf[base + (size_t)j * D_INNER] = (_Float16)yv;
            }
        }
    }
}

extern "C" void kernel_launch(void* const* d_in, const int* in_sizes, int n_in,
                              void* d_out, int out_size, void* d_ws, size_t ws_size,
                              hipStream_t stream) {
    const float* x      = (const float*)d_in[0];
    const float* W_in   = (const float*)d_in[1];
    const float* conv_w = (const float*)d_in[2];
    const float* conv_b = (const float*)d_in[3];
    const float* W_x    = (const float*)d_in[4];
    const float* W_dt   = (const float*)d_in[5];
    const float* b_dt   = (const float*)d_in[6];
    const float* A_log  = (const float*)d_in[7];
    const float* D_par  = (const float*)d_in[8];
    const float* W_out  = (const float*)d_in[9];
    float* out = (float*)d_out;

    char* wsb = (char*)d_ws;
    _Float16*  xsh    = (_Float16*)(wsb + 0);             // 16,777,216 B
    _Float16*  sresh  = (_Float16*)(wsb + 16777216);      // 16,777,216 B
    _Float16*  deltah = (_Float16*)(wsb + 33554432);      // 16,777,216 B
    _Float16*  xch    = (_Float16*)(wsb + 50331648);      // 16,777,216 B
    _Float16*  xf16   = (_Float16*)(wsb + 67108864);      //  8,388,608 B (dead after K1)
    _Float16*  WinT   = (_Float16*)(wsb + 75497472);      //  8,388,608 B (dead after K1)
    _Float16*  yhalf  = (_Float16*)(wsb + 67108864);      // 16,777,216 B (aliases xf16+WinT)
    _Float16*  WxT    = (_Float16*)(wsb + 83886080);      //    393,216 B
    _Float16*  WdtT   = (_Float16*)(wsb + 84279296);      //    262,144 B
    _Float16*  xdh    = (_Float16*)(wsb + 84541440);      //    524,288 B
    float*     Bbuf   = (float*)(wsb + 85065728);         //    262,144 B
    float*     Cbuf   = (float*)(wsb + 85327872);         //    262,144 B
    float*     Ssum   = (float*)(wsb + 85590016);         //  1,048,576 B
    float*     hloc   = (float*)(wsb + 86638592);         // 16,777,216 B
    float*     h0buf  = (float*)(wsb + 103415808);        // 16,777,216 B
    _Float16*  WoutT  = (_Float16*)(wsb + 120193024);     //  4,194,304 B
    // end: 124,387,328 B

    dim3 blk(256);

    // 1. fused prep: all weight transposes + x cast
    prep<<<dim3(10560), blk, 0, stream>>>(x, xf16, W_in, WinT, W_x, WxT,
                                          W_dt, WdtT, W_out, WoutT);
    // 2. K1: [xs fp16 | silu(res) fp16] = x @ W_in  (M=4096, N=4096, K=1024)
    gemm_f16<2><<<dim3(32, 32), blk, 0, stream>>>(
        xf16, WinT, nullptr, nullptr, xsh, sresh, MM, 2 * D_INNER, D_MODEL, 2048);
    // 3. conv + SiLU -> xch fp16
    conv_silu<<<dim3((size_t)MM * D_INNER / 8 / 256), blk, 0, stream>>>(xsh, conv_w, conv_b, xch);
    // 4. xd = xc @ W_x (skinny): xdh fp16 + B, C fp32
    gemm_xd<<<dim3(MM / 64), blk, 0, stream>>>(xch, WxT, xdh, Bbuf, Cbuf);
    // 5. delta = softplus(xd @ W_dt + b_dt) -> fp16  (M=4096, N=2048, K=64)
    gemm_f16<1><<<dim3(16, 32), blk, 0, stream>>>(
        xdh, WdtT, b_dt, nullptr, deltah, nullptr, MM, D_INNER, DT_RANK, D_INNER);
    // 6. scan pass 1
    scan_part1<<<dim3(D_INNER / 256, NCH, B_SZ), blk, 0, stream>>>(deltah, xch, Bbuf, A_log, hloc, Ssum);
    // 7. combine
    scan_combine<<<dim3(B_SZ * D_INNER * 16 / 256), blk, 0, stream>>>(hloc, Ssum, A_log, h0buf);
    // 8. scan pass 2 (+gating) -> yhalf fp16
    scan_part2<<<dim3(D_INNER / 256, NCH, B_SZ), blk, 0, stream>>>(deltah, xch, Bbuf, Cbuf, h0buf, A_log, D_par, sresh, yhalf);
    // 9. K5: out = y @ W_out  (M=4096, N=1024, K=2048)
    gemm_f16<0><<<dim3(8, 32), blk, 0, stream>>>(
        yhalf, WoutT, nullptr, out, nullptr, nullptr, MM, D_MODEL, D_INNER, D_MODEL);
}

// Round 10
// 321.234 us; speedup vs baseline: 1.2114x; 1.1455x over previous
//
#include <hip/hip_runtime.h>
#include <math.h>

#define B_SZ    2
#define L_SEQ   2048
#define D_MODEL 1024
#define D_INNER 2048
#define D_STATE 16
#define DT_RANK 64
#define MM      (B_SZ * L_SEQ)   // 4096 rows
#define NCH     64               // scan chunks
#define CLEN    (L_SEQ / NCH)    // 32 steps per chunk
#define PFD     8                // scan prefetch depth

typedef _Float16 h8v __attribute__((ext_vector_type(8)));
typedef _Float16 h4v __attribute__((ext_vector_type(4)));
typedef float f32x4 __attribute__((ext_vector_type(4)));

// Async global->LDS DMA, 16B per lane. LDS dest = uniform base + lane*16.
__device__ __forceinline__ void gload16(const void* g, void* l) {
    __builtin_amdgcn_global_load_lds((const __attribute__((address_space(1))) void*)g,
                                     (__attribute__((address_space(3))) void*)l, 16, 0, 0);
}

// ---------------------------------------------------------------------------
// prep: all weight transposes (fp32 -> fp16 T[N][K]) + x -> fp16 cast +
// conv_w transpose to [k][d] fp32 (kills conv_silu's uncoalesced weight loads).
// ---------------------------------------------------------------------------
__global__ __launch_bounds__(256) void prep(const float* __restrict__ x,
                                            _Float16* __restrict__ xf16,
                                            const float* __restrict__ W_in,
                                            _Float16* __restrict__ WinT,
                                            const float* __restrict__ W_x,
                                            _Float16* __restrict__ WxT,
                                            const float* __restrict__ W_dt,
                                            _Float16* __restrict__ WdtT,
                                            const float* __restrict__ W_out,
                                            _Float16* __restrict__ WoutT,
                                            const float* __restrict__ cw,
                                            float* __restrict__ cwT) {
    __shared__ float t[32][33];
    const int b = blockIdx.x;
    const float* W; _Float16* T; int K, N, tile;
    if (b < 4096)      { W = W_in;  T = WinT;  K = 1024; N = 4096; tile = b; }
    else if (b < 4288) { W = W_x;   T = WxT;   K = 2048; N = 96;   tile = b - 4096; }
    else if (b < 4416) { W = W_dt;  T = WdtT;  K = 64;   N = 2048; tile = b - 4288; }
    else if (b < 6464) { W = W_out; T = WoutT; K = 2048; N = 1024; tile = b - 4416; }
    else if (b < 10560) {
        int idx = (b - 6464) * 256 + threadIdx.x;
        float4 v = ((const float4*)x)[idx];
        h4v h = {(_Float16)v.x, (_Float16)v.y, (_Float16)v.z, (_Float16)v.w};
        *(h4v*)(xf16 + (size_t)idx * 4) = h;
        return;
    } else {
        // conv_w [2048][4] -> cwT [4][2048]
        for (int i = threadIdx.x; i < D_INNER * 4; i += 256) {
            int d = i >> 2, k = i & 3;
            cwT[k * D_INNER + d] = cw[i];
        }
        return;
    }
    const int ntx = N / 32;
    const int k0 = (tile / ntx) * 32, n0 = (tile % ntx) * 32;
    #pragma unroll
    for (int i = 0; i < 4; ++i) {
        int idx = threadIdx.x + i * 256;
        int r = idx >> 5, c = idx & 31;
        t[r][c] = W[(size_t)(k0 + r) * N + n0 + c];
    }
    __syncthreads();
    #pragma unroll
    for (int i = 0; i < 4; ++i) {
        int idx = threadIdx.x + i * 256;
        int n = idx >> 5, k = idx & 31;
        T[(size_t)(n0 + n) * K + k0 + k] = (_Float16)t[k][n];
    }
}

// ---------------------------------------------------------------------------
// fp16 MFMA GEMM, double-buffered async DMA: C = A[M][K] @ Bt[N][K]^T.
// 128x128 tile, 256 thr, 4 waves 2x2, wave 64x64 (4x4 16x16x32 frags), BK=32.
// K-loop: issue DMA(k+1) -> MFMA(k) -> barrier. Buffer offsets arithmetic
// (no LDS pointer arrays -- addrspacecast static-init error).
// Epilogue: per-wave LDS transpose -> vectorized 16B stores.
// EPI 0: fp32 C. EPI 1: fp16 H = softplus(acc+bias[col]).
// EPI 2: bn<2048 -> fp16 H (xs); bn>=2048 -> silu -> fp16 Hg (gate).
// ---------------------------------------------------------------------------
template<int EPI>
__global__ __launch_bounds__(256) void gemm_f16(const _Float16* __restrict__ A,
                                                const _Float16* __restrict__ Bt,
                                                const float* __restrict__ bias,
                                                float* __restrict__ C,
                                                _Float16* __restrict__ H,
                                                _Float16* __restrict__ Hg,
                                                int M, int N, int K, int ldc) {
    __shared__ _Float16 smemh[16384];   // 32KB: staging dbuf, reused by epilogue

    const int tid = threadIdx.x;
    const int wave = tid >> 6, lane = tid & 63;
    const int bm = blockIdx.y * 128, bn = blockIdx.x * 128;

    const int lrow = lane >> 2, pc = lane & 3;
    const int ar = wave * 32 + lrow;
    const size_t gA = (size_t)(bm + ar) * K + ((pc ^ ((ar >> 1) & 3)) * 8);
    const size_t gB = (size_t)(bn + ar) * K + ((pc ^ ((ar >> 1) & 3)) * 8);
    const int lofs = (wave * 32) * 32;

    const int lm = lane & 15, lq = lane >> 4;
    const int rofs = (lq ^ ((lm >> 1) & 3)) * 8;
    const int wm = (wave >> 1) * 64, wn = (wave & 1) * 64;

    f32x4 acc[4][4];
    #pragma unroll
    for (int i = 0; i < 4; ++i)
        #pragma unroll
        for (int j = 0; j < 4; ++j) acc[i][j] = (f32x4){0.f, 0.f, 0.f, 0.f};

    // prologue: fill buffer 0  (A buf at kb*4096, B buf at 8192 + kb*4096)
    gload16(A + gA, smemh + lofs);
    gload16(A + gA + (size_t)16 * K, smemh + lofs + 16 * 32);
    gload16(Bt + gB, smemh + 8192 + lofs);
    gload16(Bt + gB + (size_t)16 * K, smemh + 8192 + lofs + 16 * 32);
    __syncthreads();

    int kb = 0;
    for (int k0 = 0; k0 < K; k0 += 32, kb ^= 1) {
        if (k0 + 32 < K) {   // issue next tile BEFORE computing this one
            int nb = kb ^ 1;
            gload16(A + gA + k0 + 32, smemh + nb * 4096 + lofs);
            gload16(A + gA + k0 + 32 + (size_t)16 * K, smemh + nb * 4096 + lofs + 16 * 32);
            gload16(Bt + gB + k0 + 32, smemh + 8192 + nb * 4096 + lofs);
            gload16(Bt + gB + k0 + 32 + (size_t)16 * K, smemh + 8192 + nb * 4096 + lofs + 16 * 32);
        }

        const _Float16* sA = smemh + kb * 4096;
        const _Float16* sB = smemh + 8192 + kb * 4096;
        h8v fa[4], fb[4];
        #pragma unroll
        for (int i = 0; i < 4; ++i) {
            fa[i] = *(const h8v*)&sA[(wm + i * 16 + lm) * 32 + rofs];
            fb[i] = *(const h8v*)&sB[(wn + i * 16 + lm) * 32 + rofs];
        }
        #pragma unroll
        for (int mi = 0; mi < 4; ++mi)
            #pragma unroll
            for (int ni = 0; ni < 4; ++ni)
                acc[mi][ni] = __builtin_amdgcn_mfma_f32_16x16x32_f16(fa[mi], fb[ni], acc[mi][ni], 0, 0, 0);
        __syncthreads();   // drains next-tile DMA; protects buffer reuse
    }
    // after final barrier all waves are done with staging LDS -> reuse it.

    if (EPI == 0) {
        float* ep = (float*)smemh + wave * 1088;   // 16 x 68 fp32 (padded)
        #pragma unroll
        for (int mi = 0; mi < 4; ++mi) {
            #pragma unroll
            for (int ni = 0; ni < 4; ++ni)
                #pragma unroll
                for (int r = 0; r < 4; ++r)
                    ep[(lq * 4 + r) * 68 + ni * 16 + lm] = acc[mi][ni][r];
            int rowb = bm + wm + mi * 16;
            #pragma unroll
            for (int i = 0; i < 4; ++i) {
                int ch = lane + 64 * i;
                int row = ch >> 4, c4 = (ch & 15) * 4;
                *(float4*)&C[(size_t)(rowb + row) * ldc + bn + wn + c4] =
                    *(const float4*)&ep[row * 68 + c4];
            }
        }
    } else {
        _Float16* ep = smemh + wave * 1152;        // 16 x 72 fp16 (padded, 16B rows)
        const bool gate = (EPI == 2) && (bn >= 2048);
        _Float16* dst = gate ? Hg : H;
        const int cb = bn + wn - (gate ? 2048 : 0);
        #pragma unroll
        for (int mi = 0; mi < 4; ++mi) {
            #pragma unroll
            for (int ni = 0; ni < 4; ++ni) {
                int col = bn + wn + ni * 16 + lm;
                #pragma unroll
                for (int r = 0; r < 4; ++r) {
                    float v = acc[mi][ni][r];
                    if (EPI == 1) {
                        float a = v + bias[col];
                        v = (a > 20.f) ? a : log1pf(__expf(a));
                    } else if (gate) {
                        v = v / (1.f + __expf(-v));
                    }
                    ep[(lq * 4 + r) * 72 + ni * 16 + lm] = (_Float16)v;
                }
            }
            int rowb = bm + wm + mi * 16;
            #pragma unroll
            for (int i = 0; i < 2; ++i) {
                int ch = lane + 64 * i;
                int row = ch >> 3, c8 = (ch & 7) * 8;
                *(h8v*)&dst[(size_t)(rowb + row) * ldc + cb + c8] =
                    *(const h8v*)&ep[row * 72 + c8];
            }
        }
    }
}

// ---------------------------------------------------------------------------
// Skinny fp16 MFMA GEMM for x_dbl: xd[4096][96] = xch @ WxT^T. 64 rows/block,
// 4 waves x 16 rows x 96 cols. LDS-staged register-prefetch (proven R5/R6).
// Epilogue scatters: 0..63 -> xdh fp16, 64..79 -> Bm, 80..95 -> Cm.
// ---------------------------------------------------------------------------
__global__ __launch_bounds__(256) void gemm_xd(const _Float16* __restrict__ xch,
                                               const _Float16* __restrict__ WxT,
                                               _Float16* __restrict__ xdh,
                                               float* __restrict__ Bm,
                                               float* __restrict__ Cm) {
    __shared__ _Float16 sA[64 * 32];
    __shared__ _Float16 sB[96 * 32];
    const int tid = threadIdx.x;
    const int m0 = blockIdx.x * 64;
    const int wave = tid >> 6, lane = tid & 63;
    const int lm = lane & 15, lq = lane >> 4;
    const int rofs = (lq ^ ((lm >> 1) & 3)) * 8;

    const int wr = tid >> 2, wc = tid & 3, c0 = wc * 8;
    const int wofsA = wr * 32 + ((wc ^ ((wr >> 1) & 3)) * 8);
    const int wr2 = 64 + wr;
    const int wofsB2 = wr2 * 32 + ((wc ^ ((wr2 >> 1) & 3)) * 8);

    f32x4 acc[6];
    #pragma unroll
    for (int i = 0; i < 6; ++i) acc[i] = (f32x4){0.f, 0.f, 0.f, 0.f};

    h8v pA = *(const h8v*)(xch + (size_t)(m0 + wr) * D_INNER + c0);
    h8v pB0 = *(const h8v*)(WxT + (size_t)wr * D_INNER + c0);
    h8v pB1 = (tid < 128) ? *(const h8v*)(WxT + (size_t)wr2 * D_INNER + c0) : (h8v)0;

    for (int k0 = 0; k0 < D_INNER; k0 += 32) {
        *(h8v*)&sA[wofsA] = pA;
        *(h8v*)&sB[wofsA] = pB0;
        if (tid < 128) *(h8v*)&sB[wofsB2] = pB1;
        __syncthreads();

        if (k0 + 32 < D_INNER) {
            int kk = k0 + 32 + c0;
            pA = *(const h8v*)(xch + (size_t)(m0 + wr) * D_INNER + kk);
            pB0 = *(const h8v*)(WxT + (size_t)wr * D_INNER + kk);
            if (tid < 128) pB1 = *(const h8v*)(WxT + (size_t)wr2 * D_INNER + kk);
        }

        h8v fa = *(const h8v*)&sA[(wave * 16 + lm) * 32 + rofs];
        #pragma unroll
        for (int nf = 0; nf < 6; ++nf) {
            h8v fb = *(const h8v*)&sB[(nf * 16 + lm) * 32 + rofs];
            acc[nf] = __builtin_amdgcn_mfma_f32_16x16x32_f16(fa, fb, acc[nf], 0, 0, 0);
        }
        __syncthreads();
    }

    #pragma unroll
    for (int nf = 0; nf < 6; ++nf) {
        int col = nf * 16 + lm;
        #pragma unroll
        for (int r = 0; r < 4; ++r) {
            int row = m0 + wave * 16 + lq * 4 + r;
            float v = acc[nf][r];
            if (col < 64)      xdh[(size_t)row * 64 + col] = (_Float16)v;
            else if (col < 80) Bm[(size_t)row * 16 + (col - 64)] = v;
            else               Cm[(size_t)row * 16 + (col - 80)] = v;
        }
    }
}

// ---------------------------------------------------------------------------
// Depthwise causal conv (k=4) + bias + SiLU, 8 elements/thread.
// Weights from cwT[k][d]: 2 coalesced float4 loads per tap (was 32 scalar
// strided dwords -> L1-thrash -> 63.7us at 10% HBM BW in R9).
// ---------------------------------------------------------------------------
__global__ __launch_bounds__(256) void conv_silu(const _Float16* __restrict__ xsh,
                                                 const float* __restrict__ cwT,
                                                 const float* __restrict__ cb,
                                                 _Float16* __restrict__ xch) {
    int idx = blockIdx.x * 256 + threadIdx.x;
    int d0 = (idx * 8) & (D_INNER - 1);
    int m  = (idx * 8) >> 11;
    int l  = m & (L_SEQ - 1);
    float acc[8];
    {
        float4 c0 = *(const float4*)&cb[d0];
        float4 c1 = *(const float4*)&cb[d0 + 4];
        acc[0] = c0.x; acc[1] = c0.y; acc[2] = c0.z; acc[3] = c0.w;
        acc[4] = c1.x; acc[5] = c1.y; acc[6] = c1.z; acc[7] = c1.w;
    }
    #pragma unroll
    for (int k = 0; k < 4; ++k) {
        int ll = l - 3 + k;
        if (ll >= 0) {
            h8v v = *(const h8v*)(xsh + (size_t)(m - 3 + k) * D_INNER + d0);
            float4 w0 = *(const float4*)&cwT[k * D_INNER + d0];
            float4 w1 = *(const float4*)&cwT[k * D_INNER + d0 + 4];
            acc[0] += (float)v[0] * w0.x; acc[1] += (float)v[1] * w0.y;
            acc[2] += (float)v[2] * w0.z; acc[3] += (float)v[3] * w0.w;
            acc[4] += (float)v[4] * w1.x; acc[5] += (float)v[5] * w1.y;
            acc[6] += (float)v[6] * w1.z; acc[7] += (float)v[7] * w1.w;
        }
    }
    h8v o;
    #pragma unroll
    for (int j = 0; j < 8; ++j) {
        float s = acc[j] / (1.f + __expf(-acc[j]));
        o[j] = (_Float16)s;
    }
    *(h8v*)(xch + (size_t)idx * 8) = o;
}

// ---------------------------------------------------------------------------
// Scan pass 1: per (b, chunk, d) chunk-local final state (h0=0) + S=sum(delta).
// ---------------------------------------------------------------------------
__global__ __launch_bounds__(256) void scan_part1(const _Float16* __restrict__ deltah,
                                                  const _Float16* __restrict__ xch,
                                                  const float* __restrict__ Bm,
                                                  const float* __restrict__ A_log,
                                                  float* __restrict__ hlocal,
                                                  float* __restrict__ Ssum) {
    const int t = threadIdx.x;
    const int d = blockIdx.x * 256 + t;
    const int c = blockIdx.y;
    const int b = blockIdx.z;

    float An[16];
    {
        const float4* ap = (const float4*)(A_log + (size_t)d * 16);
        #pragma unroll
        for (int q = 0; q < 4; ++q) {
            float4 v = ap[q];
            An[q * 4 + 0] = -__expf(v.x); An[q * 4 + 1] = -__expf(v.y);
            An[q * 4 + 2] = -__expf(v.z); An[q * 4 + 3] = -__expf(v.w);
        }
    }
    const float An0 = An[0];
    bool fast = An0 < 0.f;
    #pragma unroll
    for (int n = 0; n < 16; ++n)
        fast = fast && (fabsf(An[n] - (float)(n + 1) * An0) < 1e-3f * fabsf(An[n]));

    __shared__ float sB[CLEN][16];
    {
        size_t l0 = (size_t)(b * L_SEQ + c * CLEN) * 16;
        #pragma unroll
        for (int i = 0; i < (CLEN * 16) / 256; ++i) {
            int idx = t + i * 256;
            sB[idx >> 4][idx & 15] = Bm[l0 + idx];
        }
    }
    __syncthreads();

    float h[16];
    #pragma unroll
    for (int n = 0; n < 16; ++n) h[n] = 0.f;
    float S = 0.f;

    size_t base = (size_t)(b * L_SEQ + c * CLEN) * D_INNER + d;
    float bd[PFD], bx[PFD];
    #pragma unroll
    for (int i = 0; i < PFD; ++i) {
        bd[i] = (float)deltah[base + (size_t)i * D_INNER];
        bx[i] = (float)xch[base + (size_t)i * D_INNER];
    }

    if (fast) {
        for (int jb = 0; jb < CLEN; jb += PFD) {
            #pragma unroll
            for (int i = 0; i < PFD; ++i) {
                int j = jb + i;
                float dv = bd[i], xv = bx[i];
                int jn = j + PFD;
                if (jn < CLEN) {
                    bd[i] = (float)deltah[base + (size_t)jn * D_INNER];
                    bx[i] = (float)xch[base + (size_t)jn * D_INNER];
                }
                S += dv;
                float dbx = dv * xv;
                float r = __expf(dv * An0);
                float pw = r;
                #pragma unroll
                for (int n = 0; n < 16; ++n) {
                    h[n] = pw * h[n] + dbx * sB[j][n];
                    pw *= r;
                }
            }
        }
    } else {
        for (int jb = 0; jb < CLEN; jb += PFD) {
            #pragma unroll
            for (int i = 0; i < PFD; ++i) {
                int j = jb + i;
                float dv = bd[i], xv = bx[i];
                int jn = j + PFD;
                if (jn < CLEN) {
                    bd[i] = (float)deltah[base + (size_t)jn * D_INNER];
                    bx[i] = (float)xch[base + (size_t)jn * D_INNER];
                }
                S += dv;
                float dbx = dv * xv;
                #pragma unroll
                for (int n = 0; n < 16; ++n)
                    h[n] = __expf(dv * An[n]) * h[n] + dbx * sB[j][n];
            }
        }
    }

    size_t o = ((size_t)(b * NCH + c) * D_INNER + d) * 16;
    float4* hp = (float4*)(hlocal + o);
    #pragma unroll
    for (int q = 0; q < 4; ++q)
        hp[q] = make_float4(h[q * 4], h[q * 4 + 1], h[q * 4 + 2], h[q * 4 + 3]);
    Ssum[(size_t)(b * NCH + c) * D_INNER + d] = S;
}

// ---------------------------------------------------------------------------
// Combine: sequential over NCH chunks per (b,d,n); writes each chunk's h0.
// ---------------------------------------------------------------------------
__global__ __launch_bounds__(256) void scan_combine(const float* __restrict__ hlocal,
                                                    const float* __restrict__ Ssum,
                                                    const float* __restrict__ A_log,
                                                    float* __restrict__ h0buf) {
    int gid = blockIdx.x * 256 + threadIdx.x;
    int n = gid & 15;
    int d = (gid >> 4) & (D_INNER - 1);
    int b = gid >> 15;
    float An = -__expf(A_log[(size_t)d * 16 + n]);
    float H = 0.f;
    float pS[4], pH[4];
    #pragma unroll
    for (int i = 0; i < 4; ++i) {
        size_t sc = (size_t)(b * NCH + i) * D_INNER + d;
        pS[i] = Ssum[sc];
        pH[i] = hlocal[sc * 16 + n];
    }
    for (int cb = 0; cb < NCH; cb += 4) {
        #pragma unroll
        for (int i = 0; i < 4; ++i) {
            int c = cb + i;
            float S = pS[i], hl = pH[i];
            int cn = c + 4;
            if (cn < NCH) {
                size_t sc = (size_t)(b * NCH + cn) * D_INNER + d;
                pS[i] = Ssum[sc];
                pH[i] = hlocal[sc * 16 + n];
            }
            size_t o = ((size_t)(b * NCH + c) * D_INNER + d) * 16 + n;
            h0buf[o] = H;
            H = __expf(An * S) * H + hl;
        }
    }
}

// ---------------------------------------------------------------------------
// Scan pass 2: replay from h0; y = sum_n h*C; fuse +xc*D and *pre-silu'd gate;
// write y fp16 (A-operand of the output GEMM).
// ---------------------------------------------------------------------------
__global__ __launch_bounds__(256) void scan_part2(const _Float16* __restrict__ deltah,
                                                  const _Float16* __restrict__ xch,
                                                  const float* __restrict__ Bm,
                                                  const float* __restrict__ Cm,
                                                  const float* __restrict__ h0buf,
                                                  const float* __restrict__ A_log,
                                                  const float* __restrict__ Dp,
                                                  const _Float16* __restrict__ sresh,
                                                  _Float16* __restrict__ yhalf) {
    const int t = threadIdx.x;
    const int d = blockIdx.x * 256 + t;
    const int c = blockIdx.y;
    const int b = blockIdx.z;

    float An[16];
    {
        const float4* ap = (const float4*)(A_log + (size_t)d * 16);
        #pragma unroll
        for (int q = 0; q < 4; ++q) {
            float4 v = ap[q];
            An[q * 4 + 0] = -__expf(v.x); An[q * 4 + 1] = -__expf(v.y);
            An[q * 4 + 2] = -__expf(v.z); An[q * 4 + 3] = -__expf(v.w);
        }
    }
    const float An0 = An[0];
    bool fast = An0 < 0.f;
    #pragma unroll
    for (int n = 0; n < 16; ++n)
        fast = fast && (fabsf(An[n] - (float)(n + 1) * An0) < 1e-3f * fabsf(An[n]));

    __shared__ float sB[CLEN][16];
    __shared__ float sC[CLEN][16];
    {
        size_t l0 = (size_t)(b * L_SEQ + c * CLEN) * 16;
        #pragma unroll
        for (int i = 0; i < (CLEN * 16) / 256; ++i) {
            int idx = t + i * 256;
            sB[idx >> 4][idx & 15] = Bm[l0 + idx];
            sC[idx >> 4][idx & 15] = Cm[l0 + idx];
        }
    }
    __syncthreads();

    float h[16];
    {
        size_t o = ((size_t)(b * NCH + c) * D_INNER + d) * 16;
        const float4* hp = (const float4*)(h0buf + o);
        #pragma unroll
        for (int q = 0; q < 4; ++q) {
            float4 v = hp[q];
            h[q * 4 + 0] = v.x; h[q * 4 + 1] = v.y;
            h[q * 4 + 2] = v.z; h[q * 4 + 3] = v.w;
        }
    }
    const float Dv = Dp[d];

    size_t base = (size_t)(b * L_SEQ + c * CLEN) * D_INNER + d;
    float bd[PFD], bx[PFD], bg[PFD];
    #pragma unroll
    for (int i = 0; i < PFD; ++i) {
        bd[i] = (float)deltah[base + (size_t)i * D_INNER];
        bx[i] = (float)xch[base + (size_t)i * D_INNER];
        bg[i] = (float)sresh[base + (size_t)i * D_INNER];
    }

    if (fast) {
        for (int jb = 0; jb < CLEN; jb += PFD) {
            #pragma unroll
            for (int i = 0; i < PFD; ++i) {
                int j = jb + i;
                float dv = bd[i], xv = bx[i], gv = bg[i];
                int jn = j + PFD;
                if (jn < CLEN) {
                    bd[i] = (float)deltah[base + (size_t)jn * D_INNER];
                    bx[i] = (float)xch[base + (size_t)jn * D_INNER];
                    bg[i] = (float)sresh[base + (size_t)jn * D_INNER];
                }
                float dbx = dv * xv;
                float r = __expf(dv * An0);
                float pw = r;
                float y = 0.f;
                #pragma unroll
                for (int n = 0; n < 16; ++n) {
                    h[n] = pw * h[n] + dbx * sB[j][n];
                    y += h[n] * sC[j][n];
                    pw *= r;
                }
                float yv = (y + xv * Dv) * gv;
                yhalf[base + (size_t)j * D_INNER] = (_Float16)yv;
            }
        }
    } else {
        for (int jb = 0; jb < CLEN; jb += PFD) {
            #pragma unroll
            for (int i = 0; i < PFD; ++i) {
                int j = jb + i;
                float dv = bd[i], xv = bx[i], gv = bg[i];
                int jn = j + PFD;
                if (jn < CLEN) {
                    bd[i] = (float)deltah[base + (size_t)jn * D_INNER];
                    bx[i] = (float)xch[base + (size_t)jn * D_INNER];
                    bg[i] = (float)sresh[base + (size_t)jn * D_INNER];
                }
                float dbx = dv * xv;
                float y = 0.f;
                #pragma unroll
                for (int n = 0; n < 16; ++n) {
                    h[n] = __expf(dv * An[n]) * h[n] + dbx * sB[j][n];
                    y += h[n] * sC[j][n];
                }
                float yv = (y + xv * Dv) * gv;
                yhalf[base + (size_t)j * D_INNER] = (_Float16)yv;
            }
        }
    }
}

extern "C" void kernel_launch(void* const* d_in, const int* in_sizes, int n_in,
                              void* d_out, int out_size, void* d_ws, size_t ws_size,
                              hipStream_t stream) {
    const float* x      = (const float*)d_in[0];
    const float* W_in   = (const float*)d_in[1];
    const float* conv_w = (const float*)d_in[2];
    const float* conv_b = (const float*)d_in[3];
    const float* W_x    = (const float*)d_in[4];
    const float* W_dt   = (const float*)d_in[5];
    const float* b_dt   = (const float*)d_in[6];
    const float* A_log  = (const float*)d_in[7];
    const float* D_par  = (const float*)d_in[8];
    const float* W_out  = (const float*)d_in[9];
    float* out = (float*)d_out;

    char* wsb = (char*)d_ws;
    _Float16*  xsh    = (_Float16*)(wsb + 0);             // 16,777,216 B
    _Float16*  sresh  = (_Float16*)(wsb + 16777216);      // 16,777,216 B
    _Float16*  deltah = (_Float16*)(wsb + 33554432);      // 16,777,216 B
    _Float16*  xch    = (_Float16*)(wsb + 50331648);      // 16,777,216 B
    _Float16*  xf16   = (_Float16*)(wsb + 67108864);      //  8,388,608 B (dead after K1)
    _Float16*  WinT   = (_Float16*)(wsb + 75497472);      //  8,388,608 B (dead after K1)
    _Float16*  yhalf  = (_Float16*)(wsb + 67108864);      // 16,777,216 B (aliases xf16+WinT)
    _Float16*  WxT    = (_Float16*)(wsb + 83886080);      //    393,216 B
    _Float16*  WdtT   = (_Float16*)(wsb + 84279296);      //    262,144 B
    _Float16*  xdh    = (_Float16*)(wsb + 84541440);      //    524,288 B
    float*     Bbuf   = (float*)(wsb + 85065728);         //    262,144 B
    float*     Cbuf   = (float*)(wsb + 85327872);         //    262,144 B
    float*     Ssum   = (float*)(wsb + 85590016);         //  1,048,576 B
    float*     hloc   = (float*)(wsb + 86638592);         // 16,777,216 B
    float*     h0buf  = (float*)(wsb + 103415808);        // 16,777,216 B
    _Float16*  WoutT  = (_Float16*)(wsb + 120193024);     //  4,194,304 B
    float*     cwT    = (float*)(wsb + 124387328);        //     32,768 B
    // end: 124,420,096 B

    dim3 blk(256);

    // 1. fused prep: all weight transposes + x cast + conv_w transpose
    prep<<<dim3(10561), blk, 0, stream>>>(x, xf16, W_in, WinT, W_x, WxT,
                                          W_dt, WdtT, W_out, WoutT, conv_w, cwT);
    // 2. K1: [xs fp16 | silu(res) fp16] = x @ W_in  (M=4096, N=4096, K=1024)
    gemm_f16<2><<<dim3(32, 32), blk, 0, stream>>>(
        xf16, WinT, nullptr, nullptr, xsh, sresh, MM, 2 * D_INNER, D_MODEL, 2048);
    // 3. conv + SiLU -> xch fp16  (coalesced cwT weights)
    conv_silu<<<dim3((size_t)MM * D_INNER / 8 / 256), blk, 0, stream>>>(xsh, cwT, conv_b, xch);
    // 4. xd = xc @ W_x (skinny): xdh fp16 + B, C fp32
    gemm_xd<<<dim3(MM / 64), blk, 0, stream>>>(xch, WxT, xdh, Bbuf, Cbuf);
    // 5. delta = softplus(xd @ W_dt + b_dt) -> fp16  (M=4096, N=2048, K=64)
    gemm_f16<1><<<dim3(16, 32), blk, 0, stream>>>(
        xdh, WdtT, b_dt, nullptr, deltah, nullptr, MM, D_INNER, DT_RANK, D_INNER);
    // 6. scan pass 1
    scan_part1<<<dim3(D_INNER / 256, NCH, B_SZ), blk, 0, stream>>>(deltah, xch, Bbuf, A_log, hloc, Ssum);
    // 7. combine
    scan_combine<<<dim3(B_SZ * D_INNER * 16 / 256), blk, 0, stream>>>(hloc, Ssum, A_log, h0buf);
    // 8. scan pass 2 (+gating) -> yhalf fp16
    scan_part2<<<dim3(D_INNER / 256, NCH, B_SZ), blk, 0, stream>>>(deltah, xch, Bbuf, Cbuf, h0buf, A_log, D_par, sresh, yhalf);
    // 9. K5: out = y @ W_out  (M=4096, N=1024, K=2048)
    gemm_f16<0><<<dim3(8, 32), blk, 0, stream>>>(
        yhalf, WoutT, nullptr, out, nullptr, nullptr, MM, D_MODEL, D_INNER, D_MODEL);
}